// Round 4
// baseline (244.193 us; speedup 1.0000x reference)
//
#include <hip/hip_runtime.h>

// B = 16777216 rows, 2 cols. 16384 blocks x 1024 elems, 4 elems/thread.
// R1-R3 lesson: compiler refuses deep per-wave MLP (VGPR pinned at 32-36 across
// array-hoist / named-pipeline / sched_barrier attempts), and L3-resident
// replays run at the SAME 78us as HBM replays => the wall is the per-wave
// serial structure, not memory. So: shrink the chain 4x, delete the LDS
// chunk-word roundtrip (thread's 4 elems contiguous -> in-register chain),
// one barrier instead of two, full-occupancy tiny blocks.
#define E_BLOCK 1024

#define M1f     0.2771814156f  // 0.5*(85/900)^0.25  (class-1 LDAM margin)
#define C_A1    60.0f          // za = tf*60 - 30      -> +-30
#define C_C1    (30.0f*M1f - 15.0f) // zc = tf*C_C1 + 15

#define EXP2F(v) __builtin_amdgcn_exp2f(v)   // v_exp_f32: 2^x
#define LOG2F(v) __builtin_amdgcn_logf(v)    // v_log_f32: log2(x)

// 0-encoded chain state: f==0 => empty. f,l in {-1,0,+1}. Ordered combine.
__device__ __forceinline__ void comb0(int &s, int &f, int &l, int sb, int fb, int lb) {
  s += sb + l * fb;
  f = f ? f : fb;
  l = fb ? lb : l;
}

__device__ __forceinline__ void bfly_step(int m, int lane, int &s, int &f, int &l) {
  const int os = __shfl_xor(s, m), of = __shfl_xor(f, m), ol = __shfl_xor(l, m);
  const bool up = (lane & m) != 0;
  int as = up ? os : s, af = up ? of : f, al = up ? ol : l;
  const int bs = up ? s : os, bf = up ? f : of, bl = up ? l : ol;
  comb0(as, af, al, bs, bf, bl);
  s = as; f = af; l = al;
}

// Full per-element update: loss terms + in-register ordered chain update.
__device__ __forceinline__ void elem_all(float x0, float x1, int t,
    float &wnll, float &flraw, int &cnt1,
    int &s0, int &f0, int &l0, int &s1, int &f1, int &l1) {
  const float tf  = (float)t;
  const float wgt = fmaf(tf, 0.7f, 0.15f);          // 0.15 / 0.85
  const float d   = x0 - x1;
  const float za  = fmaf(tf, C_A1, -30.0f);
  const float zc  = fmaf(tf, C_C1, 15.0f);
  const float z   = fmaf(za, d, zc);                // 30*(t? d+M1 : 0.5-d)
  const float ex  = EXP2F(fabsf(z) * -1.44269504f);
  const float lp  = LOG2F(1.0f + ex);
  const float sp  = fmaf(0.69314718f, lp, fmaxf(z, 0.0f));  // softplus(z)
  wnll = fmaf(wgt, sp, wnll);
  const float om  = 1.0f - x1;
  const float q   = t ? x1 : om;
  const float r   = t ? om : x1;
  const float lg2 = LOG2F(q + 1e-9f);
  const float wr2 = (wgt * r) * r;
  flraw = fmaf(wr2, lg2, flraw);                    // * -ln2 applied at end
  cnt1 += t;
  // chain: new same-class element with sign sv; empty chain has l==0.
  const int sv = (d > 0.0f) ? 1 : -1;
  const int lv = t ? l1 : l0;
  const int add = lv * sv;
  if (t) { s1 += add; l1 = sv; f1 = f1 ? f1 : sv; }
  else   { s0 += add; l0 = sv; f0 = f0 ? f0 : sv; }
}

__global__ __launch_bounds__(256) void loss_pass1(
    const float* __restrict__ x, const int* __restrict__ tgt,
    int4* __restrict__ recs, int B) {
  __shared__ unsigned int stw[256];
  __shared__ float wnw[256];
  __shared__ float flw[256];
  __shared__ int   cnw[256];

  const int tid = threadIdx.x;
  const int w = tid >> 6, lane = tid & 63;
  const int base = blockIdx.x * E_BLOCK + tid * 4;  // 4 contiguous elems/thread

  float wnll = 0.f, flraw = 0.f; int cnt1 = 0;
  int s0 = 0, f0 = 0, l0 = 0, s1 = 0, f1 = 0, l1 = 0;

  if (base + 4 <= B) {
    // 3 loads, used immediately: px[0]/px[1] lane-stride 32 B (the two insts
    // together cover every line), t4 dense 16 B/lane.
    const float4* __restrict__ px = (const float4*)(x + 2 * (size_t)base);
    const float4 a = px[0];
    const float4 b = px[1];
    const int4  t4 = *(const int4*)(tgt + base);
    elem_all(a.x, a.y, t4.x, wnll, flraw, cnt1, s0, f0, l0, s1, f1, l1);
    elem_all(a.z, a.w, t4.y, wnll, flraw, cnt1, s0, f0, l0, s1, f1, l1);
    elem_all(b.x, b.y, t4.z, wnll, flraw, cnt1, s0, f0, l0, s1, f1, l1);
    elem_all(b.z, b.w, t4.w, wnll, flraw, cnt1, s0, f0, l0, s1, f1, l1);
  } else {
    for (int k = 0; k < 4; ++k) {
      const int e = base + k;
      if (e < B) {
        elem_all(x[2 * (size_t)e], x[2 * (size_t)e + 1], tgt[e],
                 wnll, flraw, cnt1, s0, f0, l0, s1, f1, l1);
      }
    }
  }

  // per-thread state -> LDS (|s| <= 3, fits the +128-bias byte)
  stw[tid] = (unsigned)(s0 + 128) | ((unsigned)(f0 + 1) << 8) | ((unsigned)(l0 + 1) << 10)
           | ((unsigned)(s1 + 128) << 16) | ((unsigned)(f1 + 1) << 24) | ((unsigned)(l1 + 1) << 26);
  wnw[tid] = wnll; flw[tid] = flraw * -0.69314718f; cnw[tid] = cnt1;
  __syncthreads();

  if (w == 0) {
    int S0 = 0, F0 = 0, L0 = 0, S1 = 0, F1 = 0, L1 = 0;
    float W = 0.f, F = 0.f; int C = 0;
    #pragma unroll
    for (int q = 0; q < 4; ++q) {
      const int i = lane * 4 + q;                 // ascending element order
      const unsigned int pk = stw[i];
      comb0(S0, F0, L0, (int)(pk & 255u) - 128, (int)((pk >> 8) & 3u) - 1, (int)((pk >> 10) & 3u) - 1);
      comb0(S1, F1, L1, (int)((pk >> 16) & 255u) - 128, (int)((pk >> 24) & 3u) - 1, (int)((pk >> 26) & 3u) - 1);
      W += wnw[i]; F += flw[i]; C += cnw[i];
    }
    #pragma unroll
    for (int k = 0; k < 6; ++k) {
      const int m = 1 << k;
      bfly_step(m, lane, S0, F0, L0);
      bfly_step(m, lane, S1, F1, L1);
      W += __shfl_xor(W, m); F += __shfl_xor(F, m); C += __shfl_xor(C, m);
    }
    if (lane == 0) {
      // packed 16-B record: |S| <= 1023 (+1024 bias, 16 bits), cnt <= 1024.
      int4 rv;
      rv.x = (int)(((unsigned)(S0 + 1024) & 0xFFFFu) | ((unsigned)(S1 + 1024) << 16));
      rv.y = (int)((unsigned)(F0 + 1) | ((unsigned)(L0 + 1) << 2)
                 | ((unsigned)(F1 + 1) << 4) | ((unsigned)(L1 + 1) << 6)
                 | ((unsigned)C << 8));
      rv.z = __float_as_int(W);
      rv.w = __float_as_int(F);
      recs[blockIdx.x] = rv;
    }
  }
}

__global__ __launch_bounds__(256) void loss_pass2(
    const int4* __restrict__ recs, int NB, int B, float* __restrict__ out) {
  __shared__ int sS0[256], sF0[256], sL0[256], sS1[256], sF1[256], sL1[256], sC[256];
  __shared__ double sW[256], sFl[256];
  const int tid = threadIdx.x, w = tid >> 6, lane = tid & 63;
  const int R = (NB + 255) >> 8;

  int s0 = 0, f0 = 0, l0 = 0, s1 = 0, f1 = 0, l1 = 0;
  double W = 0.0, Fd = 0.0; int C = 0;
  #pragma unroll 4
  for (int r = 0; r < R; ++r) {
    const int b = tid * R + r;
    if (b < NB) {
      const int4 rv = recs[b];
      const unsigned u0 = (unsigned)rv.x, u1 = (unsigned)rv.y;
      comb0(s0, f0, l0, (int)(u0 & 0xFFFFu) - 1024, (int)(u1 & 3u) - 1, (int)((u1 >> 2) & 3u) - 1);
      comb0(s1, f1, l1, (int)(u0 >> 16) - 1024, (int)((u1 >> 4) & 3u) - 1, (int)((u1 >> 6) & 3u) - 1);
      W  += (double)__int_as_float(rv.z);
      Fd += (double)__int_as_float(rv.w);
      C  += (int)(u1 >> 8);
    }
  }
  sS0[tid] = s0; sF0[tid] = f0; sL0[tid] = l0;
  sS1[tid] = s1; sF1[tid] = f1; sL1[tid] = l1;
  sC[tid] = C; sW[tid] = W; sFl[tid] = Fd;
  __syncthreads();

  if (w == 0) {
    int S0 = 0, F0 = 0, L0 = 0, S1 = 0, F1 = 0, L1 = 0; int Ct = 0;
    double Wt = 0.0, Ft = 0.0;
    #pragma unroll
    for (int q = 0; q < 4; ++q) {
      const int i = lane * 4 + q;
      comb0(S0, F0, L0, sS0[i], sF0[i], sL0[i]);
      comb0(S1, F1, L1, sS1[i], sF1[i], sL1[i]);
      Wt += sW[i]; Ft += sFl[i]; Ct += sC[i];
    }
    #pragma unroll
    for (int k = 0; k < 6; ++k) {
      const int m = 1 << k;
      bfly_step(m, lane, S0, F0, L0);
      bfly_step(m, lane, S1, F1, L1);
      Wt += __shfl_xor(Wt, m); Ft += __shfl_xor(Ft, m); Ct += __shfl_xor(Ct, m);
    }
    if (lane == 0) {
      const double n1 = (double)Ct, n0 = (double)B - n1;
      const double sw = 0.15 * n0 + 0.85 * n1;
      const double ldam  = Wt / sw;
      const double focal = Ft / (double)B;
      const double q0 = (n0 > 0.0) ? (double)S0 / n0 : 0.0;
      const double q1 = (n1 > 0.0) ? (double)S1 / n1 : 0.0;
      const double dq = q0 - q1;
      out[0] = (float)(ldam + focal + dq * dq);
    }
  }
}

extern "C" void kernel_launch(void* const* d_in, const int* in_sizes, int n_in,
                              void* d_out, int out_size, void* d_ws, size_t ws_size,
                              hipStream_t stream) {
  const float* x  = (const float*)d_in[0];
  const int* tgt  = (const int*)d_in[1];
  float* out      = (float*)d_out;
  const int B  = in_sizes[1];                       // rows (16777216)
  const int NB = (B + E_BLOCK - 1) / E_BLOCK;       // 16384
  int4* recs = (int4*)d_ws;                         // 256 KB scratch
  loss_pass1<<<NB, 256, 0, stream>>>(x, tgt, recs, B);
  loss_pass2<<<1, 256, 0, stream>>>(recs, NB, B, out);
}

// Round 6
// 243.044 us; speedup vs baseline: 1.0047x; 1.0047x over previous
//
#include <hip/hip_runtime.h>

// B = 16777216 rows, 2 cols.
// R1-R4 lesson: VALU~20us busy, HBM-roofline ~32us, yet every short-lived-block
// variant pins at ~78us while the harness fill kernel hits 6.8 TB/s on the same
// GPU. Theory: pulsed per-generation memory demand + compiler-serialized loads.
// This version: 1024 persistent blocks (4/CU), contiguous 16-tile span each,
// async global_load_lds staging (MLP by construction, no VGPR payload),
// double-buffered LDS, raw s_barrier + counted vmcnt(3) (NOT __syncthreads,
// which drains vmcnt(0) and collapses the prefetch).
#define NT 16            // tiles per block
#define TE 1024          // elements per tile
#define BLK_ELEMS (NT*TE)  // 16384 contiguous elements per block

#define M1f     0.2771814156f  // 0.5*(85/900)^0.25  (class-1 LDAM margin)
#define C_A1    60.0f
#define C_C1    (30.0f*M1f - 15.0f)

#define EXP2F(v) __builtin_amdgcn_exp2f(v)
#define LOG2F(v) __builtin_amdgcn_logf(v)

// async 16-B global->LDS DMA. LDS dest is wave-uniform base + lane*16;
// global src is per-lane. size must be a literal (4/12/16).
__device__ __forceinline__ void gload16(const void* g, void* l) {
  __builtin_amdgcn_global_load_lds(
      (const __attribute__((address_space(1))) void*)g,
      (__attribute__((address_space(3))) void*)l, 16, 0, 0);
}

// 0-encoded chain state: f==0 => empty. f,l in {-1,0,+1}. Ordered combine.
__device__ __forceinline__ void comb0(int &s, int &f, int &l, int sb, int fb, int lb) {
  s += sb + l * fb;
  f = f ? f : fb;
  l = fb ? lb : l;
}

__device__ __forceinline__ void bfly_step(int m, int lane, int &s, int &f, int &l) {
  const int os = __shfl_xor(s, m), of = __shfl_xor(f, m), ol = __shfl_xor(l, m);
  const bool up = (lane & m) != 0;
  int as = up ? os : s, af = up ? of : f, al = up ? ol : l;
  const int bs = up ? s : os, bf = up ? f : of, bl = up ? l : ol;
  comb0(as, af, al, bs, bf, bl);
  s = as; f = af; l = al;
}

// Full per-element update: loss terms + in-register ordered chain update.
__device__ __forceinline__ void elem_all(float x0, float x1, int t,
    float &wnll, float &flraw, int &cnt1,
    int &s0, int &f0, int &l0, int &s1, int &f1, int &l1) {
  const float tf  = (float)t;
  const float wgt = fmaf(tf, 0.7f, 0.15f);          // 0.15 / 0.85
  const float d   = x0 - x1;
  const float za  = fmaf(tf, C_A1, -30.0f);
  const float zc  = fmaf(tf, C_C1, 15.0f);
  const float z   = fmaf(za, d, zc);                // 30*(t? d+M1 : 0.5-d)
  const float ex  = EXP2F(fabsf(z) * -1.44269504f);
  const float lp  = LOG2F(1.0f + ex);
  const float sp  = fmaf(0.69314718f, lp, fmaxf(z, 0.0f));  // softplus(z)
  wnll = fmaf(wgt, sp, wnll);
  const float om  = 1.0f - x1;
  const float q   = t ? x1 : om;
  const float r   = t ? om : x1;
  const float lg2 = LOG2F(q + 1e-9f);
  const float wr2 = (wgt * r) * r;
  flraw = fmaf(wr2, lg2, flraw);                    // * -ln2 applied at end
  cnt1 += t;
  const int sv = (d > 0.0f) ? 1 : -1;
  const int lv = t ? l1 : l0;
  const int add = lv * sv;
  if (t) { s1 += add; l1 = sv; f1 = f1 ? f1 : sv; }
  else   { s0 += add; l0 = sv; f0 = f0 ? f0 : sv; }
}

__global__ __launch_bounds__(256) void loss_pass1(
    const float* __restrict__ x, const int* __restrict__ tgt,
    int4* __restrict__ recs, int B) {
  __shared__ float4 xbuf[2][512];           // 16 KB: tile x as 512 granules
  __shared__ int4   tbuf[2][256];           //  8 KB: tile tgt as 256 granules
  __shared__ unsigned short seg[NT * 256];  //  8 KB: per-tile thread chain states
  __shared__ unsigned int stw[256];
  __shared__ float wnw[256], flw[256];
  __shared__ int   cnw[256];

  const int tid = threadIdx.x;
  const int w = tid >> 6, lane = tid & 63;
  const size_t blkBase = (size_t)blockIdx.x * BLK_ELEMS;

  float wnll = 0.f, flraw = 0.f; int cnt1 = 0;

  if (blkBase + BLK_ELEMS <= (size_t)B) {
    // ---- fast path: async double-buffered tiles ----
    const int xg = w * 128;    // this wave's x-granule base within a tile
    const int tg = w * 64;     // this wave's tgt-granule base
    {  // prologue: stage tile 0 -> buf 0 (3 DMA insts per wave)
      const float* gx = x + 2 * blkBase + (size_t)(xg + lane) * 4;
      gload16(gx,       &xbuf[0][xg]);
      gload16(gx + 256, &xbuf[0][xg + 64]);
      gload16(tgt + blkBase + (size_t)(tg + lane) * 4, &tbuf[0][tg]);
    }
    for (int k = 0; k < NT; ++k) {
      const int c = k & 1;
      if (k + 1 < NT) {
        // stage tile k+1 into the other buffer, then wait only for tile k's
        // 3 loads (3 newest stay in flight across the barrier).
        const size_t tb = blkBase + (size_t)(k + 1) * TE;
        const float* gx = x + 2 * tb + (size_t)(xg + lane) * 4;
        gload16(gx,       &xbuf[c ^ 1][xg]);
        gload16(gx + 256, &xbuf[c ^ 1][xg + 64]);
        gload16(tgt + tb + (size_t)(tg + lane) * 4, &tbuf[c ^ 1][tg]);
        asm volatile("s_waitcnt vmcnt(3)" ::: "memory");
      } else {
        asm volatile("s_waitcnt vmcnt(0)" ::: "memory");
      }
      __builtin_amdgcn_s_barrier();          // tile k fully in LDS (no drain)
      __builtin_amdgcn_sched_barrier(0);
      const float4 a  = xbuf[c][2 * tid];
      const float4 b  = xbuf[c][2 * tid + 1];
      const int4   t4 = tbuf[c][tid];
      int s0 = 0, f0 = 0, l0 = 0, s1 = 0, f1 = 0, l1 = 0;
      elem_all(a.x, a.y, t4.x, wnll, flraw, cnt1, s0, f0, l0, s1, f1, l1);
      elem_all(a.z, a.w, t4.y, wnll, flraw, cnt1, s0, f0, l0, s1, f1, l1);
      elem_all(b.x, b.y, t4.z, wnll, flraw, cnt1, s0, f0, l0, s1, f1, l1);
      elem_all(b.z, b.w, t4.w, wnll, flraw, cnt1, s0, f0, l0, s1, f1, l1);
      seg[k * 256 + tid] = (unsigned short)(
          (unsigned)(s0 + 3) | ((unsigned)(f0 + 1) << 3) | ((unsigned)(l0 + 1) << 5) |
          ((unsigned)(s1 + 3) << 7) | ((unsigned)(f1 + 1) << 10) | ((unsigned)(l1 + 1) << 12));
      if (k + 1 < NT) {                      // buf[c] free for re-stage
        __builtin_amdgcn_sched_barrier(0);
        __builtin_amdgcn_s_barrier();
        __builtin_amdgcn_sched_barrier(0);
      }
    }
  } else {
    // ---- guarded fallback: direct global, per-element bounds check ----
    for (int k = 0; k < NT; ++k) {
      int s0 = 0, f0 = 0, l0 = 0, s1 = 0, f1 = 0, l1 = 0;
      for (int e = 0; e < 4; ++e) {
        const size_t idx = blkBase + (size_t)k * TE + (size_t)tid * 4 + e;
        if (idx < (size_t)B)
          elem_all(x[2 * idx], x[2 * idx + 1], tgt[idx],
                   wnll, flraw, cnt1, s0, f0, l0, s1, f1, l1);
      }
      seg[k * 256 + tid] = (unsigned short)(
          (unsigned)(s0 + 3) | ((unsigned)(f0 + 1) << 3) | ((unsigned)(l0 + 1) << 5) |
          ((unsigned)(s1 + 3) << 7) | ((unsigned)(f1 + 1) << 10) | ((unsigned)(l1 + 1) << 12));
    }
  }
  __syncthreads();   // all seg[] visible (also drains any residual counts)

  // Combine 16 thread-segments each, preserving element order:
  // partial t covers tile (t>>4), threads [(t&15)*16, +16)  -> ascending order.
  {
    int s0 = 0, f0 = 0, l0 = 0, s1 = 0, f1 = 0, l1 = 0;
    const int base = (tid >> 4) * 256 + (tid & 15) * 16;
    #pragma unroll
    for (int j = 0; j < 16; ++j) {
      const unsigned v = seg[base + j];
      comb0(s0, f0, l0, (int)(v & 7u) - 3, (int)((v >> 3) & 3u) - 1, (int)((v >> 5) & 3u) - 1);
      comb0(s1, f1, l1, (int)((v >> 7) & 7u) - 3, (int)((v >> 10) & 3u) - 1, (int)((v >> 12) & 3u) - 1);
    }
    // |s| <= 63 fits the +128-bias byte
    stw[tid] = (unsigned)(s0 + 128) | ((unsigned)(f0 + 1) << 8) | ((unsigned)(l0 + 1) << 10)
             | ((unsigned)(s1 + 128) << 16) | ((unsigned)(f1 + 1) << 24) | ((unsigned)(l1 + 1) << 26);
    wnw[tid] = wnll; flw[tid] = flraw * -0.69314718f; cnw[tid] = cnt1;
  }
  __syncthreads();

  if (w == 0) {
    int S0 = 0, F0 = 0, L0 = 0, S1 = 0, F1 = 0, L1 = 0;
    float W = 0.f, F = 0.f; int C = 0;
    #pragma unroll
    for (int q = 0; q < 4; ++q) {
      const int i = lane * 4 + q;                 // ascending partial order
      const unsigned int pk = stw[i];
      comb0(S0, F0, L0, (int)(pk & 255u) - 128, (int)((pk >> 8) & 3u) - 1, (int)((pk >> 10) & 3u) - 1);
      comb0(S1, F1, L1, (int)((pk >> 16) & 255u) - 128, (int)((pk >> 24) & 3u) - 1, (int)((pk >> 26) & 3u) - 1);
      W += wnw[i]; F += flw[i]; C += cnw[i];
    }
    #pragma unroll
    for (int k = 0; k < 6; ++k) {
      const int m = 1 << k;
      bfly_step(m, lane, S0, F0, L0);
      bfly_step(m, lane, S1, F1, L1);
      W += __shfl_xor(W, m); F += __shfl_xor(F, m); C += __shfl_xor(C, m);
    }
    if (lane == 0) {
      // |S| <= 16383: 16-bit with +16384 bias. C <= 16384: bits 8..23 of y.
      int4 rv;
      rv.x = (int)(((unsigned)(S0 + 16384) & 0xFFFFu) | ((unsigned)(S1 + 16384) << 16));
      rv.y = (int)((unsigned)(F0 + 1) | ((unsigned)(L0 + 1) << 2)
                 | ((unsigned)(F1 + 1) << 4) | ((unsigned)(L1 + 1) << 6)
                 | ((unsigned)C << 8));
      rv.z = __float_as_int(W);
      rv.w = __float_as_int(F);
      recs[blockIdx.x] = rv;
    }
  }
}

__global__ __launch_bounds__(256) void loss_pass2(
    const int4* __restrict__ recs, int NB, int B, float* __restrict__ out) {
  __shared__ int sS0[256], sF0[256], sL0[256], sS1[256], sF1[256], sL1[256], sC[256];
  __shared__ double sW[256], sFl[256];
  const int tid = threadIdx.x, w = tid >> 6, lane = tid & 63;
  const int R = (NB + 255) >> 8;

  int s0 = 0, f0 = 0, l0 = 0, s1 = 0, f1 = 0, l1 = 0;
  double W = 0.0, Fd = 0.0; int C = 0;
  for (int r = 0; r < R; ++r) {
    const int b = tid * R + r;
    if (b < NB) {
      const int4 rv = recs[b];
      const unsigned u0 = (unsigned)rv.x, u1 = (unsigned)rv.y;
      comb0(s0, f0, l0, (int)(u0 & 0xFFFFu) - 16384, (int)(u1 & 3u) - 1, (int)((u1 >> 2) & 3u) - 1);
      comb0(s1, f1, l1, (int)(u0 >> 16) - 16384, (int)((u1 >> 4) & 3u) - 1, (int)((u1 >> 6) & 3u) - 1);
      W  += (double)__int_as_float(rv.z);
      Fd += (double)__int_as_float(rv.w);
      C  += (int)(u1 >> 8);
    }
  }
  sS0[tid] = s0; sF0[tid] = f0; sL0[tid] = l0;
  sS1[tid] = s1; sF1[tid] = f1; sL1[tid] = l1;
  sC[tid] = C; sW[tid] = W; sFl[tid] = Fd;
  __syncthreads();

  if (w == 0) {
    int S0 = 0, F0 = 0, L0 = 0, S1 = 0, F1 = 0, L1 = 0; int Ct = 0;
    double Wt = 0.0, Ft = 0.0;
    #pragma unroll
    for (int q = 0; q < 4; ++q) {
      const int i = lane * 4 + q;
      comb0(S0, F0, L0, sS0[i], sF0[i], sL0[i]);
      comb0(S1, F1, L1, sS1[i], sF1[i], sL1[i]);
      Wt += sW[i]; Ft += sFl[i]; Ct += sC[i];
    }
    #pragma unroll
    for (int k = 0; k < 6; ++k) {
      const int m = 1 << k;
      bfly_step(m, lane, S0, F0, L0);
      bfly_step(m, lane, S1, F1, L1);
      Wt += __shfl_xor(Wt, m); Ft += __shfl_xor(Ft, m); Ct += __shfl_xor(Ct, m);
    }
    if (lane == 0) {
      const double n1 = (double)Ct, n0 = (double)B - n1;
      const double sw = 0.15 * n0 + 0.85 * n1;
      const double ldam  = Wt / sw;
      const double focal = Ft / (double)B;
      const double q0 = (n0 > 0.0) ? (double)S0 / n0 : 0.0;
      const double q1 = (n1 > 0.0) ? (double)S1 / n1 : 0.0;
      const double dq = q0 - q1;
      out[0] = (float)(ldam + focal + dq * dq);
    }
  }
}

extern "C" void kernel_launch(void* const* d_in, const int* in_sizes, int n_in,
                              void* d_out, int out_size, void* d_ws, size_t ws_size,
                              hipStream_t stream) {
  const float* x  = (const float*)d_in[0];
  const int* tgt  = (const int*)d_in[1];
  float* out      = (float*)d_out;
  const int B  = in_sizes[1];                        // rows (16777216)
  const int NB = (B + BLK_ELEMS - 1) / BLK_ELEMS;    // 1024
  int4* recs = (int4*)d_ws;                          // 16 KB scratch
  loss_pass1<<<NB, 256, 0, stream>>>(x, tgt, recs, B);
  loss_pass2<<<1, 256, 0, stream>>>(recs, NB, B, out);
}

// Round 7
// 240.351 us; speedup vs baseline: 1.0160x; 1.0112x over previous
//
#include <hip/hip_runtime.h>

// B = 16777216 rows, 2 cols. 2048 blocks x 8192 elems; single generation
// (8 blocks/CU co-resident), NO barriers in the main loop, fully dense loads.
// R1-R6 invariant: ~20us VALU issue, runtime ~78us, logical read ~2.6 TB/s
// across every structure. This round separates "read-path cap" (T-A) from
// "convoyed waves" (T-B): free-running waves, 8 independent iterations each,
// per-lane 2-elem chain segments -> own LDS slot (no sync), one final barrier.

#define M1f     0.2771814156f  // 0.5*(85/900)^0.25  (class-1 LDAM margin)
#define C_A1    60.0f
#define C_C1    (30.0f*M1f - 15.0f)

#define EXP2F(v) __builtin_amdgcn_exp2f(v)
#define LOG2F(v) __builtin_amdgcn_logf(v)

// 0-encoded chain state: f==0 => empty. f,l in {-1,0,+1}. Ordered combine.
__device__ __forceinline__ void comb0(int &s, int &f, int &l, int sb, int fb, int lb) {
  s += sb + l * fb;
  f = f ? f : fb;
  l = fb ? lb : l;
}

__device__ __forceinline__ void bfly_step(int m, int lane, int &s, int &f, int &l) {
  const int os = __shfl_xor(s, m), of = __shfl_xor(f, m), ol = __shfl_xor(l, m);
  const bool up = (lane & m) != 0;
  int as = up ? os : s, af = up ? of : f, al = up ? ol : l;
  const int bs = up ? s : os, bf = up ? f : of, bl = up ? l : ol;
  comb0(as, af, al, bs, bf, bl);
  s = as; f = af; l = al;
}

// Full per-element update: loss terms + in-register ordered chain update.
__device__ __forceinline__ void elem_all(float x0, float x1, int t,
    float &wnll, float &flraw, int &cnt1,
    int &s0, int &f0, int &l0, int &s1, int &f1, int &l1) {
  const float tf  = (float)t;
  const float wgt = fmaf(tf, 0.7f, 0.15f);          // 0.15 / 0.85
  const float d   = x0 - x1;
  const float za  = fmaf(tf, C_A1, -30.0f);
  const float zc  = fmaf(tf, C_C1, 15.0f);
  const float z   = fmaf(za, d, zc);                // 30*(t? d+M1 : 0.5-d)
  const float ex  = EXP2F(fabsf(z) * -1.44269504f);
  const float lp  = LOG2F(1.0f + ex);
  const float sp  = fmaf(0.69314718f, lp, fmaxf(z, 0.0f));  // softplus(z)
  wnll = fmaf(wgt, sp, wnll);
  const float om  = 1.0f - x1;
  const float q   = t ? x1 : om;
  const float r   = t ? om : x1;
  const float lg2 = LOG2F(q + 1e-9f);
  const float wr2 = (wgt * r) * r;
  flraw = fmaf(wr2, lg2, flraw);                    // * -ln2 applied at end
  cnt1 += t;
  const int sv = (d > 0.0f) ? 1 : -1;
  const int lv = t ? l1 : l0;
  const int add = lv * sv;
  if (t) { s1 += add; l1 = sv; f1 = f1 ? f1 : sv; }
  else   { s0 += add; l0 = sv; f0 = f0 ? f0 : sv; }
}

// pack a 2-elem segment state for one class into 6 bits: s+1 | (f+1)<<2 | (l+1)<<4
__device__ __forceinline__ unsigned pack6(int s, int f, int l) {
  return (unsigned)(s + 1) | ((unsigned)(f + 1) << 2) | ((unsigned)(l + 1) << 4);
}

__global__ __launch_bounds__(256) void loss_pass1(
    const float* __restrict__ x, const int* __restrict__ tgt,
    int4* __restrict__ recs, int B) {
  // segw: 2048 state words + pad word every 16 (conflict-free 16-run reads).
  __shared__ unsigned int segw[2176];
  __shared__ unsigned int stw[256];
  __shared__ float wnw[256], flw[256];
  __shared__ int   cnw[256];

  const int tid = threadIdx.x;
  const int w = tid >> 6, lane = tid & 63;
  const size_t blkBase = (size_t)blockIdx.x * 8192;

  float wnll = 0.f, flraw = 0.f; int cnt1 = 0;

  if (blkBase + 8192 <= (size_t)B) {
    // fast path: 8 independent iterations, 4 dense loads each, no barriers.
    #pragma unroll
    for (int it = 0; it < 8; ++it) {
      const size_t Wb = blkBase + (size_t)it * 1024 + (size_t)w * 256;
      // wave-tile = 256 elems. lane i owns pairs (Wb+2i, +1) and (Wb+128+2i, +1).
      const float4 xlo = *(const float4*)(x + 2 * Wb + 4 * (size_t)lane);
      const float4 xhi = *(const float4*)(x + 2 * Wb + 256 + 4 * (size_t)lane);
      const int2   tlo = *(const int2*)(tgt + Wb + 2 * (size_t)lane);
      const int2   thi = *(const int2*)(tgt + Wb + 128 + 2 * (size_t)lane);

      int sA0 = 0, fA0 = 0, lA0 = 0, sA1 = 0, fA1 = 0, lA1 = 0;
      elem_all(xlo.x, xlo.y, tlo.x, wnll, flraw, cnt1, sA0, fA0, lA0, sA1, fA1, lA1);
      elem_all(xlo.z, xlo.w, tlo.y, wnll, flraw, cnt1, sA0, fA0, lA0, sA1, fA1, lA1);
      int sB0 = 0, fB0 = 0, lB0 = 0, sB1 = 0, fB1 = 0, lB1 = 0;
      elem_all(xhi.x, xhi.y, thi.x, wnll, flraw, cnt1, sB0, fB0, lB0, sB1, fB1, lB1);
      elem_all(xhi.z, xhi.w, thi.y, wnll, flraw, cnt1, sB0, fB0, lB0, sB1, fB1, lB1);

      const unsigned pa = pack6(sA0, fA0, lA0) | (pack6(sA1, fA1, lA1) << 6);
      const unsigned pb = pack6(sB0, fB0, lB0) | (pack6(sB1, fB1, lB1) << 6);
      const int W = it * 256 + tid;          // own slot: no sync needed
      segw[W + (W >> 4)] = pa | (pb << 12);
    }
  } else {
    // guarded path (identical layout, per-element bounds checks)
    for (int it = 0; it < 8; ++it) {
      const size_t Wb = blkBase + (size_t)it * 1024 + (size_t)w * 256;
      int sA0 = 0, fA0 = 0, lA0 = 0, sA1 = 0, fA1 = 0, lA1 = 0;
      int sB0 = 0, fB0 = 0, lB0 = 0, sB1 = 0, fB1 = 0, lB1 = 0;
      for (int k = 0; k < 2; ++k) {
        const size_t eA = Wb + 2 * (size_t)lane + k;
        if (eA < (size_t)B)
          elem_all(x[2 * eA], x[2 * eA + 1], tgt[eA], wnll, flraw, cnt1,
                   sA0, fA0, lA0, sA1, fA1, lA1);
        const size_t eB = Wb + 128 + 2 * (size_t)lane + k;
        if (eB < (size_t)B)
          elem_all(x[2 * eB], x[2 * eB + 1], tgt[eB], wnll, flraw, cnt1,
                   sB0, fB0, lB0, sB1, fB1, lB1);
      }
      const unsigned pa = pack6(sA0, fA0, lA0) | (pack6(sA1, fA1, lA1) << 6);
      const unsigned pb = pack6(sB0, fB0, lB0) | (pack6(sB1, fB1, lB1) << 6);
      const int W = it * 256 + tid;
      segw[W + (W >> 4)] = pa | (pb << 12);
    }
  }
  __syncthreads();   // single barrier: all 2048 segment words visible

  // Each thread combines 16 consecutive segments (global order within block:
  // g = it*512 + w*128 + half*64 + lane). 16 | 64 => run stays in one
  // (it,w,half); word = it*256 + w*64 + lane, field at 12*half.
  {
    int s0 = 0, f0 = 0, l0 = 0, s1 = 0, f1 = 0, l1 = 0;
    const int g0 = tid * 16;
    const int it = g0 >> 9, wv = (g0 >> 7) & 3, half = (g0 >> 6) & 1;
    const int lb = g0 & 63;
    const int sh = half * 12;
    const int Wbase = it * 256 + wv * 64 + lb;
    #pragma unroll
    for (int j = 0; j < 16; ++j) {
      const int W = Wbase + j;
      const unsigned v = (segw[W + (W >> 4)] >> sh) & 0xFFFu;
      comb0(s0, f0, l0, (int)(v & 3u) - 1, (int)((v >> 2) & 3u) - 1, (int)((v >> 4) & 3u) - 1);
      comb0(s1, f1, l1, (int)((v >> 6) & 3u) - 1, (int)((v >> 8) & 3u) - 1, (int)((v >> 10) & 3u) - 1);
    }
    // |s| <= 31 fits the +128-bias byte
    stw[tid] = (unsigned)(s0 + 128) | ((unsigned)(f0 + 1) << 8) | ((unsigned)(l0 + 1) << 10)
             | ((unsigned)(s1 + 128) << 16) | ((unsigned)(f1 + 1) << 24) | ((unsigned)(l1 + 1) << 26);
    wnw[tid] = wnll; flw[tid] = flraw * -0.69314718f; cnw[tid] = cnt1;
  }
  __syncthreads();

  if (w == 0) {
    int S0 = 0, F0 = 0, L0 = 0, S1 = 0, F1 = 0, L1 = 0;
    float W = 0.f, F = 0.f; int C = 0;
    #pragma unroll
    for (int q = 0; q < 4; ++q) {
      const int i = lane * 4 + q;                 // ascending partial order
      const unsigned int pk = stw[i];
      comb0(S0, F0, L0, (int)(pk & 255u) - 128, (int)((pk >> 8) & 3u) - 1, (int)((pk >> 10) & 3u) - 1);
      comb0(S1, F1, L1, (int)((pk >> 16) & 255u) - 128, (int)((pk >> 24) & 3u) - 1, (int)((pk >> 26) & 3u) - 1);
      W += wnw[i]; F += flw[i]; C += cnw[i];
    }
    #pragma unroll
    for (int k = 0; k < 6; ++k) {
      const int m = 1 << k;
      bfly_step(m, lane, S0, F0, L0);
      bfly_step(m, lane, S1, F1, L1);
      W += __shfl_xor(W, m); F += __shfl_xor(F, m); C += __shfl_xor(C, m);
    }
    if (lane == 0) {
      // |S| <= 8191: 16-bit with +8192 bias. C <= 8192 in bits 8..23 of y.
      int4 rv;
      rv.x = (int)(((unsigned)(S0 + 8192) & 0xFFFFu) | ((unsigned)(S1 + 8192) << 16));
      rv.y = (int)((unsigned)(F0 + 1) | ((unsigned)(L0 + 1) << 2)
                 | ((unsigned)(F1 + 1) << 4) | ((unsigned)(L1 + 1) << 6)
                 | ((unsigned)C << 8));
      rv.z = __float_as_int(W);
      rv.w = __float_as_int(F);
      recs[blockIdx.x] = rv;
    }
  }
}

__global__ __launch_bounds__(256) void loss_pass2(
    const int4* __restrict__ recs, int NB, int B, float* __restrict__ out) {
  __shared__ int sS0[256], sF0[256], sL0[256], sS1[256], sF1[256], sL1[256], sC[256];
  __shared__ double sW[256], sFl[256];
  const int tid = threadIdx.x, w = tid >> 6, lane = tid & 63;
  const int R = (NB + 255) >> 8;

  int s0 = 0, f0 = 0, l0 = 0, s1 = 0, f1 = 0, l1 = 0;
  double W = 0.0, Fd = 0.0; int C = 0;
  for (int r = 0; r < R; ++r) {
    const int b = tid * R + r;
    if (b < NB) {
      const int4 rv = recs[b];
      const unsigned u0 = (unsigned)rv.x, u1 = (unsigned)rv.y;
      comb0(s0, f0, l0, (int)(u0 & 0xFFFFu) - 8192, (int)(u1 & 3u) - 1, (int)((u1 >> 2) & 3u) - 1);
      comb0(s1, f1, l1, (int)(u0 >> 16) - 8192, (int)((u1 >> 4) & 3u) - 1, (int)((u1 >> 6) & 3u) - 1);
      W  += (double)__int_as_float(rv.z);
      Fd += (double)__int_as_float(rv.w);
      C  += (int)(u1 >> 8);
    }
  }
  sS0[tid] = s0; sF0[tid] = f0; sL0[tid] = l0;
  sS1[tid] = s1; sF1[tid] = f1; sL1[tid] = l1;
  sC[tid] = C; sW[tid] = W; sFl[tid] = Fd;
  __syncthreads();

  if (w == 0) {
    int S0 = 0, F0 = 0, L0 = 0, S1 = 0, F1 = 0, L1 = 0; int Ct = 0;
    double Wt = 0.0, Ft = 0.0;
    #pragma unroll
    for (int q = 0; q < 4; ++q) {
      const int i = lane * 4 + q;
      comb0(S0, F0, L0, sS0[i], sF0[i], sL0[i]);
      comb0(S1, F1, L1, sS1[i], sF1[i], sL1[i]);
      Wt += sW[i]; Ft += sFl[i]; Ct += sC[i];
    }
    #pragma unroll
    for (int k = 0; k < 6; ++k) {
      const int m = 1 << k;
      bfly_step(m, lane, S0, F0, L0);
      bfly_step(m, lane, S1, F1, L1);
      Wt += __shfl_xor(Wt, m); Ft += __shfl_xor(Ft, m); Ct += __shfl_xor(Ct, m);
    }
    if (lane == 0) {
      const double n1 = (double)Ct, n0 = (double)B - n1;
      const double sw = 0.15 * n0 + 0.85 * n1;
      const double ldam  = Wt / sw;
      const double focal = Ft / (double)B;
      const double q0 = (n0 > 0.0) ? (double)S0 / n0 : 0.0;
      const double q1 = (n1 > 0.0) ? (double)S1 / n1 : 0.0;
      const double dq = q0 - q1;
      out[0] = (float)(ldam + focal + dq * dq);
    }
  }
}

extern "C" void kernel_launch(void* const* d_in, const int* in_sizes, int n_in,
                              void* d_out, int out_size, void* d_ws, size_t ws_size,
                              hipStream_t stream) {
  const float* x  = (const float*)d_in[0];
  const int* tgt  = (const int*)d_in[1];
  float* out      = (float*)d_out;
  const int B  = in_sizes[1];                 // rows (16777216)
  const int NB = (B + 8191) >> 13;            // 2048
  int4* recs = (int4*)d_ws;                   // 32 KB scratch
  loss_pass1<<<NB, 256, 0, stream>>>(x, tgt, recs, B);
  loss_pass2<<<1, 256, 0, stream>>>(recs, NB, B, out);
}

// Round 8
// 234.754 us; speedup vs baseline: 1.0402x; 1.0238x over previous
//
#include <hip/hip_runtime.h>

// B = 16777216 rows, 2 cols. 4096 blocks x 4096 elems, 16 elems/thread.
// R1-R7: every C-level MLP attempt was vetoed by the compiler (VGPR 32-52
// every round => <=3 loads in flight); dur invariant 76-88us, VALUBusy ~25%,
// L3-resident == HBM-resident. This round forces MLP with inline-asm
// global_load_dwordx4 (volatile => program order, cannot be sunk/spilled by
// the scheduler) + hand-counted s_waitcnt vmcnt(9/6/3/0) + sched_barrier(0)
// fences (rule: "memory" clobber does not order register-only consumers).

typedef float  f4 __attribute__((ext_vector_type(4)));
typedef int    i4 __attribute__((ext_vector_type(4)));

#define M1f     0.2771814156f  // 0.5*(85/900)^0.25  (class-1 LDAM margin)
#define C_A1    60.0f
#define C_C1    (30.0f*M1f - 15.0f)

#define EXP2F(v) __builtin_amdgcn_exp2f(v)
#define LOG2F(v) __builtin_amdgcn_logf(v)

// 0-encoded chain state: f==0 => empty. f,l in {-1,0,+1}. Ordered combine.
__device__ __forceinline__ void comb0(int &s, int &f, int &l, int sb, int fb, int lb) {
  s += sb + l * fb;
  f = f ? f : fb;
  l = fb ? lb : l;
}

__device__ __forceinline__ void bfly_step(int m, int lane, int &s, int &f, int &l) {
  const int os = __shfl_xor(s, m), of = __shfl_xor(f, m), ol = __shfl_xor(l, m);
  const bool up = (lane & m) != 0;
  int as = up ? os : s, af = up ? of : f, al = up ? ol : l;
  const int bs = up ? s : os, bf = up ? f : of, bl = up ? l : ol;
  comb0(as, af, al, bs, bf, bl);
  s = as; f = af; l = al;
}

// Per-element: loss terms + in-register ordered chain update (quad-local).
__device__ __forceinline__ void elem_all(float x0, float x1, int t,
    float &wnll, float &flraw, int &cnt1,
    int &s0, int &f0, int &l0, int &s1, int &f1, int &l1) {
  const float tf  = (float)t;
  const float wgt = fmaf(tf, 0.7f, 0.15f);          // 0.15 / 0.85
  const float d   = x0 - x1;
  const float za  = fmaf(tf, C_A1, -30.0f);
  const float zc  = fmaf(tf, C_C1, 15.0f);
  const float z   = fmaf(za, d, zc);                // 30*(t? d+M1 : 0.5-d)
  const float ex  = EXP2F(fabsf(z) * -1.44269504f);
  const float lp  = LOG2F(1.0f + ex);
  const float sp  = fmaf(0.69314718f, lp, fmaxf(z, 0.0f));  // softplus(z)
  wnll = fmaf(wgt, sp, wnll);
  const float om  = 1.0f - x1;
  const float q   = t ? x1 : om;
  const float r   = t ? om : x1;
  const float lg2 = LOG2F(q + 1e-9f);
  const float wr2 = (wgt * r) * r;
  flraw = fmaf(wr2, lg2, flraw);                    // * -ln2 applied at end
  cnt1 += t;
  const int sv = (d > 0.0f) ? 1 : -1;
  const int lv = t ? l1 : l0;
  const int add = lv * sv;
  if (t) { s1 += add; l1 = sv; f1 = f1 ? f1 : sv; }
  else   { s0 += add; l0 = sv; f0 = f0 ? f0 : sv; }
}

__global__ __launch_bounds__(256) void loss_pass1(
    const float* __restrict__ x, const int* __restrict__ tgt,
    i4* __restrict__ recs, int B) {
  __shared__ unsigned short seg[1024];  // per-quad chain states (elem order)
  __shared__ unsigned int stw[256];
  __shared__ float wnw[256], flw[256];
  __shared__ int   cnw[256];

  const int tid = threadIdx.x;
  const int w = tid >> 6, lane = tid & 63;
  const size_t eb = (size_t)blockIdx.x * 4096;

  float wnll = 0.f, flraw = 0.f; int cnt1 = 0;

  if (eb + 4096 <= (size_t)B) {
    // fast path: 12 asm loads issued back-to-back (program order guaranteed
    // by volatile), consumed quad-by-quad behind counted vmcnt waits.
    f4 a0, a1, a2, a3, b0, b1, b2, b3;
    i4 t0, t1, t2, t3;
    // iteration it: wave tile = eb + it*1024 + w*256; lane quad = +lane*4.
    const float* xq = x + 2 * (eb + (size_t)w * 256) + 8 * (size_t)lane;
    const int*   tq = tgt + (eb + (size_t)w * 256) + 4 * (size_t)lane;
    #define ISSUE(A, BV, T, OFS) \
      asm volatile("global_load_dwordx4 %0, %1, off" : "=v"(A) : "v"(xq + 2048*(OFS))     : "memory"); \
      asm volatile("global_load_dwordx4 %0, %1, off" : "=v"(BV) : "v"(xq + 2048*(OFS) + 4) : "memory"); \
      asm volatile("global_load_dwordx4 %0, %1, off" : "=v"(T) : "v"(tq + 1024*(OFS))     : "memory")
    ISSUE(a0, b0, t0, 0);
    ISSUE(a1, b1, t1, 1);
    ISSUE(a2, b2, t2, 2);
    ISSUE(a3, b3, t3, 3);
    #undef ISSUE

    #define CONSUME(A, BV, T, IT, CNT) \
      { \
        asm volatile("s_waitcnt vmcnt(" #CNT ")" ::: "memory"); \
        __builtin_amdgcn_sched_barrier(0); \
        int s0 = 0, f0 = 0, l0 = 0, s1 = 0, f1 = 0, l1 = 0; \
        elem_all(A.x, A.y, T.x, wnll, flraw, cnt1, s0, f0, l0, s1, f1, l1); \
        elem_all(A.z, A.w, T.y, wnll, flraw, cnt1, s0, f0, l0, s1, f1, l1); \
        elem_all(BV.x, BV.y, T.z, wnll, flraw, cnt1, s0, f0, l0, s1, f1, l1); \
        elem_all(BV.z, BV.w, T.w, wnll, flraw, cnt1, s0, f0, l0, s1, f1, l1); \
        seg[(IT) * 256 + w * 64 + lane] = (unsigned short)( \
            (unsigned)(s0 + 3) | ((unsigned)(f0 + 1) << 3) | ((unsigned)(l0 + 1) << 5) | \
            ((unsigned)(s1 + 3) << 7) | ((unsigned)(f1 + 1) << 10) | ((unsigned)(l1 + 1) << 12)); \
      }
    CONSUME(a0, b0, t0, 0, 9)
    CONSUME(a1, b1, t1, 1, 6)
    CONSUME(a2, b2, t2, 2, 3)
    CONSUME(a3, b3, t3, 3, 0)
    #undef CONSUME
  } else {
    // guarded path: per-element bounds check, same seg layout
    for (int it = 0; it < 4; ++it) {
      int s0 = 0, f0 = 0, l0 = 0, s1 = 0, f1 = 0, l1 = 0;
      for (int k = 0; k < 4; ++k) {
        const size_t e = eb + (size_t)it * 1024 + (size_t)w * 256 + 4 * (size_t)lane + k;
        if (e < (size_t)B)
          elem_all(x[2 * e], x[2 * e + 1], tgt[e], wnll, flraw, cnt1,
                   s0, f0, l0, s1, f1, l1);
      }
      seg[it * 256 + w * 64 + lane] = (unsigned short)(
          (unsigned)(s0 + 3) | ((unsigned)(f0 + 1) << 3) | ((unsigned)(l0 + 1) << 5) |
          ((unsigned)(s1 + 3) << 7) | ((unsigned)(f1 + 1) << 10) | ((unsigned)(l1 + 1) << 12));
    }
  }
  __syncthreads();

  // Phase 2: thread t combines quads 4t..4t+3 = elements 16t..16t+15 (ordered:
  // quad qi covers elems eb+4*qi..+3, written at seg[qi]).
  {
    int s0 = 0, f0 = 0, l0 = 0, s1 = 0, f1 = 0, l1 = 0;
    #pragma unroll
    for (int j = 0; j < 4; ++j) {
      const unsigned v = seg[tid * 4 + j];
      comb0(s0, f0, l0, (int)(v & 7u) - 3, (int)((v >> 3) & 3u) - 1, (int)((v >> 5) & 3u) - 1);
      comb0(s1, f1, l1, (int)((v >> 7) & 7u) - 3, (int)((v >> 10) & 3u) - 1, (int)((v >> 12) & 3u) - 1);
    }
    // |s| <= 15 fits the +128-bias byte
    stw[tid] = (unsigned)(s0 + 128) | ((unsigned)(f0 + 1) << 8) | ((unsigned)(l0 + 1) << 10)
             | ((unsigned)(s1 + 128) << 16) | ((unsigned)(f1 + 1) << 24) | ((unsigned)(l1 + 1) << 26);
    wnw[tid] = wnll; flw[tid] = flraw * -0.69314718f; cnw[tid] = cnt1;
  }
  __syncthreads();

  if (w == 0) {
    int S0 = 0, F0 = 0, L0 = 0, S1 = 0, F1 = 0, L1 = 0;
    float W = 0.f, F = 0.f; int C = 0;
    #pragma unroll
    for (int q = 0; q < 4; ++q) {
      const int i = lane * 4 + q;                 // ascending partial order
      const unsigned int pk = stw[i];
      comb0(S0, F0, L0, (int)(pk & 255u) - 128, (int)((pk >> 8) & 3u) - 1, (int)((pk >> 10) & 3u) - 1);
      comb0(S1, F1, L1, (int)((pk >> 16) & 255u) - 128, (int)((pk >> 24) & 3u) - 1, (int)((pk >> 26) & 3u) - 1);
      W += wnw[i]; F += flw[i]; C += cnw[i];
    }
    #pragma unroll
    for (int k = 0; k < 6; ++k) {
      const int m = 1 << k;
      bfly_step(m, lane, S0, F0, L0);
      bfly_step(m, lane, S1, F1, L1);
      W += __shfl_xor(W, m); F += __shfl_xor(F, m); C += __shfl_xor(C, m);
    }
    if (lane == 0) {
      // |S| <= 4095: 16-bit with +8192 bias. C <= 4096 in bits 8..23 of y.
      i4 rv;
      rv.x = (int)(((unsigned)(S0 + 8192) & 0xFFFFu) | ((unsigned)(S1 + 8192) << 16));
      rv.y = (int)((unsigned)(F0 + 1) | ((unsigned)(L0 + 1) << 2)
                 | ((unsigned)(F1 + 1) << 4) | ((unsigned)(L1 + 1) << 6)
                 | ((unsigned)C << 8));
      rv.z = __float_as_int(W);
      rv.w = __float_as_int(F);
      recs[blockIdx.x] = rv;
    }
  }
}

__global__ __launch_bounds__(256) void loss_pass2(
    const i4* __restrict__ recs, int NB, int B, float* __restrict__ out) {
  __shared__ int sS0[256], sF0[256], sL0[256], sS1[256], sF1[256], sL1[256], sC[256];
  __shared__ double sW[256], sFl[256];
  const int tid = threadIdx.x, w = tid >> 6, lane = tid & 63;
  const int R = (NB + 255) >> 8;

  int s0 = 0, f0 = 0, l0 = 0, s1 = 0, f1 = 0, l1 = 0;
  double W = 0.0, Fd = 0.0; int C = 0;
  for (int r = 0; r < R; ++r) {
    const int b = tid * R + r;
    if (b < NB) {
      const i4 rv = recs[b];
      const unsigned u0 = (unsigned)rv.x, u1 = (unsigned)rv.y;
      comb0(s0, f0, l0, (int)(u0 & 0xFFFFu) - 8192, (int)(u1 & 3u) - 1, (int)((u1 >> 2) & 3u) - 1);
      comb0(s1, f1, l1, (int)(u0 >> 16) - 8192, (int)((u1 >> 4) & 3u) - 1, (int)((u1 >> 6) & 3u) - 1);
      W  += (double)__int_as_float(rv.z);
      Fd += (double)__int_as_float(rv.w);
      C  += (int)(u1 >> 8);
    }
  }
  sS0[tid] = s0; sF0[tid] = f0; sL0[tid] = l0;
  sS1[tid] = s1; sF1[tid] = f1; sL1[tid] = l1;
  sC[tid] = C; sW[tid] = W; sFl[tid] = Fd;
  __syncthreads();

  if (w == 0) {
    int S0 = 0, F0 = 0, L0 = 0, S1 = 0, F1 = 0, L1 = 0; int Ct = 0;
    double Wt = 0.0, Ft = 0.0;
    #pragma unroll
    for (int q = 0; q < 4; ++q) {
      const int i = lane * 4 + q;
      comb0(S0, F0, L0, sS0[i], sF0[i], sL0[i]);
      comb0(S1, F1, L1, sS1[i], sF1[i], sL1[i]);
      Wt += sW[i]; Ft += sFl[i]; Ct += sC[i];
    }
    #pragma unroll
    for (int k = 0; k < 6; ++k) {
      const int m = 1 << k;
      bfly_step(m, lane, S0, F0, L0);
      bfly_step(m, lane, S1, F1, L1);
      Wt += __shfl_xor(Wt, m); Ft += __shfl_xor(Ft, m); Ct += __shfl_xor(Ct, m);
    }
    if (lane == 0) {
      const double n1 = (double)Ct, n0 = (double)B - n1;
      const double sw = 0.15 * n0 + 0.85 * n1;
      const double ldam  = Wt / sw;
      const double focal = Ft / (double)B;
      const double q0 = (n0 > 0.0) ? (double)S0 / n0 : 0.0;
      const double q1 = (n1 > 0.0) ? (double)S1 / n1 : 0.0;
      const double dq = q0 - q1;
      out[0] = (float)(ldam + focal + dq * dq);
    }
  }
}

extern "C" void kernel_launch(void* const* d_in, const int* in_sizes, int n_in,
                              void* d_out, int out_size, void* d_ws, size_t ws_size,
                              hipStream_t stream) {
  const float* x  = (const float*)d_in[0];
  const int* tgt  = (const int*)d_in[1];
  float* out      = (float*)d_out;
  const int B  = in_sizes[1];                 // rows (16777216)
  const int NB = (B + 4095) >> 12;            // 4096
  i4* recs = (i4*)d_ws;                       // 64 KB scratch
  loss_pass1<<<NB, 256, 0, stream>>>(x, tgt, recs, B);
  loss_pass2<<<1, 256, 0, stream>>>(recs, NB, B, out);
}